// Round 20
// baseline (1323.173 us; speedup 1.0000x reference)
//
#include <hip/hip_runtime.h>

#define D0 64
#define D1 1024
#define D2 1024
#define KST 10                 // ALL 10 timesteps in one pass
#define W   64                 // d2 strip width incl. 2*KST halo
#define TT  44                 // valid strip width = W - 2*KST
#define NSTRIP 24              // 24*44 = 1056 >= 1024
#define NSEG 10
#define SEGLEN 103
#define NWG (NSTRIP * NSEG)    // 240 <= 256: one block per CU, single round
#define COEFF 0.05f
#define CHALF 0.025f
#define PS2 (D0 * W / 2)       // u32 (bf16x2) per LDS plane = 2048
#define ROWSTR ((size_t)D1 * (size_t)D2)

typedef float4 f4;
typedef float __attribute__((ext_vector_type(2))) f2;
typedef unsigned int u32;
typedef unsigned short u16;

struct PG { static constexpr bool steady = false; static constexpr int par = 0; };
struct P0 { static constexpr bool steady = true;  static constexpr int par = 0; };
struct P1 { static constexpr bool steady = true;  static constexpr int par = 1; };

__device__ __forceinline__ f4 ld4(const float* p) { return *(const f4*)p; }
__device__ __forceinline__ void st4(float* p, f4 v) { *(f4*)p = v; }
__device__ __forceinline__ f2 mk2(float a, float b) { f2 v; v.x = a; v.y = b; return v; }
__device__ __forceinline__ int clampi(int v, int lo, int hi) {
    v = v < lo ? lo : v; return v > hi ? hi : v;
}

// ---- bf16 pack/unpack (v_perm pack). Rings are bf16; derivative weight
// <= 0.05 so truncation error stays small; center path is f32 registers. ----
__device__ __forceinline__ u32 pk(float a, float b) {
    return __builtin_amdgcn_perm(__float_as_uint(b), __float_as_uint(a), 0x07060302u);
}
__device__ __forceinline__ uint2 pk4(f4 v) { return make_uint2(pk(v.x, v.y), pk(v.z, v.w)); }
__device__ __forceinline__ f4 upk4(uint2 w) {
    return make_float4(__uint_as_float(w.x << 16), __uint_as_float(w.x & 0xFFFF0000u),
                       __uint_as_float(w.y << 16), __uint_as_float(w.y & 0xFFFF0000u));
}
__device__ __forceinline__ uint2 ld2u(const u32* p) { return *(const uint2*)p; }
__device__ __forceinline__ void stb(u32* p, f4 v) { *(uint2*)p = pk4(v); }

// m204 bijective XCD-chunk swizzle, NWG=240 (q=30, r=0).
__device__ __forceinline__ int swz(int orig) {
    const int q = NWG / 8, rr = NWG % 8;
    const int xcd = orig & 7, sub = orig >> 3;
    const int base = (xcd < rr) ? xcd * (q + 1) : rr * (q + 1) + (xcd - rr) * q;
    return base + sub;
}

// lane i <- lane i-1 (row_shr:1). 16 threads/row: DPP 16-lane groups align one
// row; invalid lanes are c4==0 / c4==60 -> inside sacrificial halo (valid
// cols [10,53]).
__device__ __forceinline__ float dpp_shr1(float x) {
    return __int_as_float(__builtin_amdgcn_update_dpp(0, __float_as_int(x), 0x111, 0xf, 0xf, true));
}
__device__ __forceinline__ float dpp_shl1(float x) {
    return __int_as_float(__builtin_amdgcn_update_dpp(0, __float_as_int(x), 0x101, 0xf, 0xf, true));
}

// Packed-f32 stencil (v_pk_fma_f32 path): 2 DPP + ~12 pk-ops per f4.
template<bool FIX2>
__device__ __forceinline__ f4 sten(f4 c, f4 zm, f4 zp, f4 um, f4 dn,
                                   float csr, f4 cx, float czf, int xlo, int xhi) {
    f4 xm = make_float4(dpp_shr1(c.w), c.x, c.y, c.z);
    f4 xp = make_float4(c.y, c.z, c.w, dpp_shl1(c.x));
    if (FIX2) {
        if (xlo == 0) xm.x = c.x;
        if (xlo == 1) xm.y = c.y;
        if (xlo == 2) xm.z = c.z;
        if (xlo == 3) xm.w = c.w;
        if (xhi == 0) xp.x = c.x;
        if (xhi == 1) xp.y = c.y;
        if (xhi == 2) xp.z = c.z;
        if (xhi == 3) xp.w = c.w;
    }
    f2 dx0 = mk2(xp.x, xp.y) - mk2(xm.x, xm.y);
    f2 dx1 = mk2(xp.z, xp.w) - mk2(xm.z, xm.w);
    f2 dy0 = mk2(dn.x, dn.y) - mk2(um.x, um.y);
    f2 dy1 = mk2(dn.z, dn.w) - mk2(um.z, um.w);
    f2 dz0 = mk2(zp.x, zp.y) - mk2(zm.x, zm.y);
    f2 dz1 = mk2(zp.z, zp.w) - mk2(zm.z, zm.w);
    f2 o0 = mk2(c.x, c.y) + mk2(cx.x, cx.y) * dx0 + csr * dy0 + czf * dz0;
    f2 o1 = mk2(c.z, c.w) + mk2(cx.z, cx.w) * dx1 + csr * dy1 + czf * dz1;
    return make_float4(o0.x, o0.y, o1.x, o1.y);
}

// SINGLE PASS, 10 stages. f32 src -> f32 dst (no intermediate global).
// LDS: 20 bf16 planes = ring s (s=0..9) x 2 slots at planes 2s, 2s+1.
// Lag-1: at iter t stage s computes plane p = t-s; reads ring[s-1] slot
// (t-s)&1 (written last iter), writes ring[s] same slot; same-iter write to
// ring[s-1] goes to the opposite parity -> race-free, one barrier per iter.
template<bool FIX2>
__device__ __forceinline__ void run(const float* __restrict__ src, float* __restrict__ dst,
                                    u32* lds, int r, int c4, int h2, int a, int bE) {
    const int off_c  = r * (W / 2) + (c4 >> 1);
    const int off_up = ((r == 0      ? 0      : r - 1)) * (W / 2) + (c4 >> 1);
    const int off_dn = ((r == D0 - 1 ? D0 - 1 : r + 1)) * (W / 2) + (c4 >> 1);
    const float csr = (r == 0 || r == D0 - 1) ? COEFF : CHALF;

    f4 cx;
    {
        const int gb = h2 + c4;
        cx.x = (gb + 0 == 0 || gb + 0 == D2 - 1) ? COEFF : CHALF;
        cx.y = (gb + 1 == 0 || gb + 1 == D2 - 1) ? COEFF : CHALF;
        cx.z = (gb + 2 == 0 || gb + 2 == D2 - 1) ? COEFF : CHALF;
        cx.w = (gb + 3 == 0 || gb + 3 == D2 - 1) ? COEFF : CHALF;
    }
    int xlo = -1, xhi = -1;
    if (FIX2) {
        const int aa = -(h2 + c4);
        const int bb = (D2 - 1) - (h2 + c4);
        if (aa >= 0 && aa < 4) xlo = aa;
        if (bb >= 0 && bb < 4) xhi = bb;
    }

    int gc0, gc1, gc2, gc3;
    if (FIX2) {
        gc0 = clampi(h2 + c4 + 0, 0, D2 - 1);
        gc1 = clampi(h2 + c4 + 1, 0, D2 - 1);
        gc2 = clampi(h2 + c4 + 2, 0, D2 - 1);
        gc3 = clampi(h2 + c4 + 3, 0, D2 - 1);
    } else {
        gc0 = h2 + c4;
    }
    auto gload = [&](int p) -> f4 {
        const float* pp = src + (size_t)r * ROWSTR + (size_t)p * D2;
        if (FIX2) return make_float4(pp[gc0], pp[gc1], pp[gc2], pp[gc3]);
        return ld4(pp + gc0);
    };

    float* dbf = dst + (size_t)r * ROWSTR + h2;

    const int t0   = max(a - KST, 0);
    const int hiIn = min(bE + KST, D1);
    // stage-s activity window: t-s in [loS, hiS)
    const int lo1 = max(a - 9, 0), hi1 = min(bE + 9, D1);
    const int lo2 = max(a - 8, 0), hi2 = min(bE + 8, D1);
    const int lo3 = max(a - 7, 0), hi3 = min(bE + 7, D1);
    const int lo4 = max(a - 6, 0), hi4 = min(bE + 6, D1);
    const int lo5 = max(a - 5, 0), hi5 = min(bE + 5, D1);
    const int lo6 = max(a - 4, 0), hi6 = min(bE + 4, D1);
    const int lo7 = max(a - 3, 0), hi7 = min(bE + 3, D1);
    const int lo8 = max(a - 2, 0), hi8 = min(bE + 2, D1);
    const int lo9 = max(a - 1, 0), hi9 = min(bE + 1, D1);
    const int lo10 = a,            hi10 = bE;

    // register state: input lags + 9 stage lag pairs
    f4 l0, l1, nxt;
    f4 s1l0, s1l1, s2l0, s2l1, s3l0, s3l1, s4l0, s4l1;
    f4 s5l0, s5l1, s6l0, s6l1, s7l0, s7l1, s8l0, s8l1, s9l0, s9l1;

    nxt = gload(t0);
    l0 = l1 = nxt;
    s1l0 = s1l1 = s2l0 = s2l1 = s3l0 = s3l1 = nxt;
    s4l0 = s4l1 = s5l0 = s5l1 = s6l0 = s6l1 = nxt;
    s7l0 = s7l1 = s8l0 = s8l1 = s9l0 = s9l1 = nxt;

    auto body = [&](int t, auto TAG) __attribute__((always_inline)) {
        constexpr bool ST = decltype(TAG)::steady;
        constexpr int PAR = decltype(TAG)::par;

        f4 tmp = gload(min(t + 1, D1 - 1));   // distance-1 global prefetch

        f4 nv1 = s1l0, nv2 = s2l0, nv3 = s3l0, nv4 = s4l0, nv5 = s5l0;
        f4 nv6 = s6l0, nv7 = s7l0, nv8 = s8l0, nv9 = s9l0;

        // ---- stage 1: input regs + ring0 -> ring1 ----
        if (ST || (t - 1 >= lo1 && t - 1 < hi1)) {
            const int p = t - 1;
            const int sl = ST ? ((PAR + 1) & 1) : (p & 1);
            f4 c  = l0;
            f4 zm = (!ST && p == 0)      ? c : l1;
            f4 zp = (!ST && p == D1 - 1) ? c : nxt;
            const float czf = (!ST && (p == 0 || p == D1 - 1)) ? COEFF : CHALF;
            const u32* pl = lds + sl * PS2;
            f4 um = upk4(ld2u(pl + off_up)), dn = upk4(ld2u(pl + off_dn));
            nv1 = sten<FIX2>(c, zm, zp, um, dn, csr, cx, czf, xlo, xhi);
            stb(lds + (2 + sl) * PS2 + off_c, nv1);
        }

#define SG(S, L0v, L1v, NVp, NV)                                                 \
        if (ST || (t - (S) >= lo##S && t - (S) < hi##S)) {                       \
            const int p = t - (S);                                               \
            const int sl = ST ? ((PAR + (S)) & 1) : (p & 1);                     \
            f4 c  = L0v;                                                         \
            f4 zm = (!ST && p == 0)      ? c : L1v;                              \
            f4 zp = (!ST && p == D1 - 1) ? c : NVp;                              \
            const float czf = (!ST && (p == 0 || p == D1 - 1)) ? COEFF : CHALF;  \
            const u32* pl = lds + (2 * ((S) - 1) + sl) * PS2;                    \
            f4 um = upk4(ld2u(pl + off_up)), dn = upk4(ld2u(pl + off_dn));       \
            NV = sten<FIX2>(c, zm, zp, um, dn, csr, cx, czf, xlo, xhi);          \
            stb(lds + (2 * (S) + sl) * PS2 + off_c, NV);                         \
        }
        SG(2, s1l0, s1l1, nv1, nv2)
        SG(3, s2l0, s2l1, nv2, nv3)
        SG(4, s3l0, s3l1, nv3, nv4)
        SG(5, s4l0, s4l1, nv4, nv5)
        SG(6, s5l0, s5l1, nv5, nv6)
        SG(7, s6l0, s6l1, nv6, nv7)
        SG(8, s7l0, s7l1, nv7, nv8)
        SG(9, s8l0, s8l1, nv8, nv9)
#undef SG

        // ---- stage 10: ring9 + s9 lags -> global f32 ----
        if (ST || (t - 10 >= lo10 && t - 10 < hi10)) {
            const int p = t - 10;
            const int sl = ST ? (PAR & 1) : (p & 1);
            f4 c  = s9l0;
            f4 zm = (!ST && p == 0)      ? c : s9l1;
            f4 zp = (!ST && p == D1 - 1) ? c : nv9;
            const float czf = (!ST && (p == 0 || p == D1 - 1)) ? COEFF : CHALF;
            const u32* pl = lds + (18 + sl) * PS2;
            f4 um = upk4(ld2u(pl + off_up)), dn = upk4(ld2u(pl + off_dn));
            f4 o = sten<FIX2>(c, zm, zp, um, dn, csr, cx, czf, xlo, xhi);
            float* dp = dbf + (size_t)p * D2;
            // valid cols [KST, W-1-KST] = [10, 53]
            if (c4 >= 12 && c4 <= 48) {
                st4(dp + c4, o);
            } else if (c4 == 8) {               // cols 10,11
                *(float2*)(dp + 10) = make_float2(o.z, o.w);
            } else if (c4 == 52) {              // cols 52,53
                *(float2*)(dp + 52) = make_float2(o.x, o.y);
            }                                   // c4==0,4,56,60: all halo
        }

        // ---- commit input plane t ----
        if (ST || t < hiIn) stb(lds + (ST ? PAR : (t & 1)) * PS2 + off_c, nxt);

        // ---- roll lags ----
        l1 = l0; l0 = nxt; nxt = tmp;
        s1l1 = s1l0; s1l0 = nv1;
        s2l1 = s2l0; s2l0 = nv2;
        s3l1 = s3l0; s3l0 = nv3;
        s4l1 = s4l0; s4l0 = nv4;
        s5l1 = s5l0; s5l0 = nv5;
        s6l1 = s6l0; s6l0 = nv6;
        s7l1 = s7l0; s7l0 = nv7;
        s8l1 = s8l0; s8l0 = nv8;
        s9l1 = s9l0; s9l0 = nv9;
        __syncthreads();
    };

    int tSlo = t0 + 2 * KST + 1;
    tSlo += (tSlo & 1);
    const int tShi = min(bE + KST - 1, D1 - 1);
    const int tEnd = bE + KST - 1;
    int t = t0;
    const int tP = min(tSlo, tEnd + 1);
#pragma unroll 1
    for (; t < tP; ++t) body(t, PG{});
#pragma unroll 1
    for (; t + 1 <= tShi; t += 2) { body(t, P0{}); body(t + 1, P1{}); }
#pragma unroll 1
    for (; t <= tEnd; ++t) body(t, PG{});
}

// __launch_bounds__(1024, 4): a 16-wave block already forces >= 4 waves/EU,
// so min=4 is truthful and raises the allocator's VGPR budget to 128 —
// enough for the ~115-VGPR 10-stage state. Plain (1024) targeted 64 VGPR
// and spilled (R19: WRITE 1.13 GB scratch). LDS = 20 planes = 163840 B
// -> exactly 1 block/CU regardless of VGPR.
template<int DUMMY>
__global__ __launch_bounds__(1024, 4) void diffusion_fused(const float* __restrict__ src,
                                                           float* __restrict__ dst) {
    __shared__ __align__(16) u32 lds[20 * PS2];   // 163840 B

    const int b = swz(blockIdx.x);
    const int seg = b / NSTRIP;
    const int strip = b - seg * NSTRIP;
    const int o2 = min(strip * TT, D2 - TT);
    const int h2 = o2 - KST;
    const int a  = seg * SEGLEN;
    const int bE = min(a + SEGLEN, D1);

    const int r  = threadIdx.x >> 4;          // 0..63 over d0 (no halo)
    const int c4 = (threadIdx.x & 15) << 2;   // 0..60 over d2 strip

    if (o2 == 0 || o2 == D2 - TT) run<true >(src, dst, &lds[0], r, c4, h2, a, bE);
    else                          run<false>(src, dst, &lds[0], r, c4, h2, a, bE);
}

extern "C" void kernel_launch(void* const* d_in, const int* in_sizes, int n_in,
                              void* d_out, int out_size, void* d_ws, size_t ws_size,
                              hipStream_t stream) {
    const float* x   = (const float*)d_in[0];
    float*       out = (float*)d_out;

    const dim3 grid(NWG);
    const dim3 block(1024);

    diffusion_fused<0><<<grid, block, 0, stream>>>(x, out);   // all 10 steps
}

// Round 21
// 330.905 us; speedup vs baseline: 3.9987x; 3.9987x over previous
//
#include <hip/hip_runtime.h>

#define D0 64
#define D1 1024
#define D2 1024
#define KST 5
#define W   64                 // d2 strip width incl. 2*KST halo
#define TT  54                 // valid strip width
#define NSTRIP 19              // ceil(1024/54)
#define NSEG 13
#define SEGLEN 79
#define NWG (NSTRIP * NSEG)    // 247 <= 256: one block per CU, single round
#define COEFF 0.05f
#define CHALF 0.025f
#define PS2 (D0 * W / 2)       // u32 (bf16x2) per LDS plane = 2048
#define ROWSTR ((size_t)D1 * (size_t)D2)

typedef float4 f4;
typedef float __attribute__((ext_vector_type(2))) f2;
typedef unsigned int u32;
typedef unsigned short u16;

struct PG { static constexpr bool steady = false; static constexpr int par = 0; };
struct P0 { static constexpr bool steady = true;  static constexpr int par = 0; };
struct P1 { static constexpr bool steady = true;  static constexpr int par = 1; };

__device__ __forceinline__ f4 ld4(const float* p) { return *(const f4*)p; }
__device__ __forceinline__ void st4(float* p, f4 v) { *(f4*)p = v; }
__device__ __forceinline__ f2 mk2(float a, float b) { f2 v; v.x = a; v.y = b; return v; }
__device__ __forceinline__ int clampi(int v, int lo, int hi) {
    v = v < lo ? lo : v; return v > hi ? hi : v;
}

// ---- bf16 pack/unpack (v_perm pack, selector verified R6). Truncation into
// LDS rings fine: ring values feed derivative terms with weight <= 0.05. ----
__device__ __forceinline__ u32 pk(float a, float b) {
    return __builtin_amdgcn_perm(__float_as_uint(b), __float_as_uint(a), 0x07060302u);
}
__device__ __forceinline__ uint2 pk4(f4 v) { return make_uint2(pk(v.x, v.y), pk(v.z, v.w)); }
__device__ __forceinline__ f4 upk4(uint2 w) {
    return make_float4(__uint_as_float(w.x << 16), __uint_as_float(w.x & 0xFFFF0000u),
                       __uint_as_float(w.y << 16), __uint_as_float(w.y & 0xFFFF0000u));
}
__device__ __forceinline__ uint2 ld2u(const u32* p) { return *(const uint2*)p; }
__device__ __forceinline__ void stb(u32* p, f4 v) { *(uint2*)p = pk4(v); }
__device__ __forceinline__ float bf2f(u16 h) { return __uint_as_float((u32)h << 16); }
__device__ __forceinline__ u16 f2bf(float f) {      // RTNE
    u32 u = __float_as_uint(f);
    u += 0x7FFFu + ((u >> 16) & 1u);
    return (u16)(u >> 16);
}

// m204 bijective XCD-chunk swizzle, NWG=247 (q=30, r=7).
__device__ __forceinline__ int swz(int orig) {
    const int q = NWG / 8, rr = NWG % 8;
    const int xcd = orig & 7, sub = orig >> 3;
    const int base = (xcd < rr) ? xcd * (q + 1) : rr * (q + 1) + (xcd - rr) * q;
    return base + sub;
}

// lane i <- lane i-1 (row_shr:1). 16 threads/row: DPP 16-lane groups align one
// row; invalid lanes are c4==0 / c4==60 -> fully inside sacrificial halo
// (valid cols [5,58]).
__device__ __forceinline__ float dpp_shr1(float x) {
    return __int_as_float(__builtin_amdgcn_update_dpp(0, __float_as_int(x), 0x111, 0xf, 0xf, true));
}
__device__ __forceinline__ float dpp_shl1(float x) {
    return __int_as_float(__builtin_amdgcn_update_dpp(0, __float_as_int(x), 0x101, 0xf, 0xf, true));
}

// Packed-f32 stencil (v_pk_fma_f32 path): 2 DPP + ~12 pk-ops per f4.
template<bool FIX2>
__device__ __forceinline__ f4 sten(f4 c, f4 zm, f4 zp, f4 um, f4 dn,
                                   float csr, f4 cx, float czf, int xlo, int xhi) {
    f4 xm = make_float4(dpp_shr1(c.w), c.x, c.y, c.z);
    f4 xp = make_float4(c.y, c.z, c.w, dpp_shl1(c.x));
    if (FIX2) {
        if (xlo == 0) xm.x = c.x;
        if (xlo == 1) xm.y = c.y;
        if (xlo == 2) xm.z = c.z;
        if (xlo == 3) xm.w = c.w;
        if (xhi == 0) xp.x = c.x;
        if (xhi == 1) xp.y = c.y;
        if (xhi == 2) xp.z = c.z;
        if (xhi == 3) xp.w = c.w;
    }
    f2 dx0 = mk2(xp.x, xp.y) - mk2(xm.x, xm.y);
    f2 dx1 = mk2(xp.z, xp.w) - mk2(xm.z, xm.w);
    f2 dy0 = mk2(dn.x, dn.y) - mk2(um.x, um.y);
    f2 dy1 = mk2(dn.z, dn.w) - mk2(um.z, um.w);
    f2 dz0 = mk2(zp.x, zp.y) - mk2(zm.x, zm.y);
    f2 dz1 = mk2(zp.z, zp.w) - mk2(zm.z, zm.w);
    f2 o0 = mk2(c.x, c.y) + mk2(cx.x, cx.y) * dx0 + csr * dy0 + czf * dz0;
    f2 o1 = mk2(c.z, c.w) + mk2(cx.z, cx.w) * dx1 + csr * dy1 + czf * dz1;
    return make_float4(o0.x, o0.y, o1.x, o1.y);
}

// PASS 0: f32 src -> bf16 ws.  PASS 1: bf16 ws -> f32 dst.
// LDS: 10 bf16 planes. 0,1 = input ring; 2+2(s-1)+k = stage-s ring. Lag-1:
// at iter t stage s computes plane p = t-s. LDS um/dn reads issued 1-2 stages
// ahead of use (parity argument: stage-s read slot (t-s)&1 vs same-iter write
// slot (t-s+1)&1 -> hazard-free).
template<int PASS, bool FIX2>
__device__ __forceinline__ void run(const void* __restrict__ srcv, void* __restrict__ dstv,
                                    u32* lds, int r, int c4, int h2, int a, int bE) {
    const float* srcf = (const float*)srcv;
    const u16*   srch = (const u16*)srcv;
    u16*   dsth = (u16*)dstv;
    float* dstf = (float*)dstv;

    const int off_c  = r * (W / 2) + (c4 >> 1);
    const int off_up = ((r == 0      ? 0      : r - 1)) * (W / 2) + (c4 >> 1);
    const int off_dn = ((r == D0 - 1 ? D0 - 1 : r + 1)) * (W / 2) + (c4 >> 1);
    const float csr = (r == 0 || r == D0 - 1) ? COEFF : CHALF;

    f4 cx;
    {
        const int gb = h2 + c4;
        cx.x = (gb + 0 == 0 || gb + 0 == D2 - 1) ? COEFF : CHALF;
        cx.y = (gb + 1 == 0 || gb + 1 == D2 - 1) ? COEFF : CHALF;
        cx.z = (gb + 2 == 0 || gb + 2 == D2 - 1) ? COEFF : CHALF;
        cx.w = (gb + 3 == 0 || gb + 3 == D2 - 1) ? COEFF : CHALF;
    }
    int xlo = -1, xhi = -1;
    if (FIX2) {
        const int aa = -(h2 + c4);
        const int bb = (D2 - 1) - (h2 + c4);
        if (aa >= 0 && aa < 4) xlo = aa;
        if (bb >= 0 && bb < 4) xhi = bb;
    }

    int gc0, gc1, gc2, gc3;
    if (FIX2) {
        gc0 = clampi(h2 + c4 + 0, 0, D2 - 1);
        gc1 = clampi(h2 + c4 + 1, 0, D2 - 1);
        gc2 = clampi(h2 + c4 + 2, 0, D2 - 1);
        gc3 = clampi(h2 + c4 + 3, 0, D2 - 1);
    } else {
        gc0 = h2 + c4; gc1 = gc0 + 1; gc2 = gc0 + 2; gc3 = gc0 + 3;
    }
    auto gload = [&](int p) -> f4 {
        if (PASS == 0) {
            const float* pp = srcf + (size_t)r * ROWSTR + (size_t)p * D2;
            if (FIX2) return make_float4(pp[gc0], pp[gc1], pp[gc2], pp[gc3]);
            return ld4(pp + gc0);
        } else {
            const u16* pp = srch + (size_t)r * ROWSTR + (size_t)p * D2;
            return make_float4(bf2f(pp[gc0]), bf2f(pp[gc1]), bf2f(pp[gc2]), bf2f(pp[gc3]));
        }
    };

    u16*   dbh = dsth + (size_t)r * ROWSTR + h2;
    float* dbf = dstf + (size_t)r * ROWSTR + h2;

    const int t0   = max(a - KST, 0);
    const int hiIn = min(bE + KST, D1);
    const int lo1 = max(a - 4, 0), hi1 = min(bE + 4, D1);
    const int lo2 = max(a - 3, 0), hi2 = min(bE + 3, D1);
    const int lo3 = max(a - 2, 0), hi3 = min(bE + 2, D1);
    const int lo4 = max(a - 1, 0), hi4 = min(bE + 1, D1);
    const int lo5 = a,             hi5 = bE;

    f4 l0, l1, nxt, nx2;
    f4 s1l0, s1l1, s2l0, s2l1, s3l0, s3l1, s4l0, s4l1;

    nxt = gload(t0);
    nx2 = gload(min(t0 + 1, D1 - 1));
    l0 = l1 = nxt;
    s1l0 = s1l1 = s2l0 = s2l1 = nxt;
    s3l0 = s3l1 = s4l0 = s4l1 = nxt;

    auto body = [&](int t, auto TAG) __attribute__((always_inline)) {
        constexpr bool ST = decltype(TAG)::steady;
        constexpr int PAR = decltype(TAG)::par;

        f4 tmp = gload(min(t + 2, D1 - 1));   // distance-2 global prefetch

        const bool a1 = ST || (t - 1 >= lo1 && t - 1 < hi1);
        const bool a2 = ST || (t - 2 >= lo2 && t - 2 < hi2);
        const bool a3 = ST || (t - 3 >= lo3 && t - 3 < hi3);
        const bool a4 = ST || (t - 4 >= lo4 && t - 4 < hi4);
        const bool a5 = ST || (t - 5 >= lo5 && t - 5 < hi5);
        const int sl1 = ST ? (PAR ^ 1) : ((t - 1) & 1);
        const int sl2 = ST ? (PAR    ) : ((t - 2) & 1);
        const int sl3 = ST ? (PAR ^ 1) : ((t - 3) & 1);
        const int sl4 = ST ? (PAR    ) : ((t - 4) & 1);
        const int sl5 = ST ? (PAR ^ 1) : ((t - 5) & 1);

        // ---- issue LDS reads for stages 1-3 (raw uint2, unpack at use) ----
        uint2 w_um1 = {0, 0}, w_dn1 = {0, 0}, w_um2 = {0, 0}, w_dn2 = {0, 0};
        uint2 w_um3 = {0, 0}, w_dn3 = {0, 0};
        if (a1) { const u32* pl = lds + sl1 * PS2;       w_um1 = ld2u(pl + off_up); w_dn1 = ld2u(pl + off_dn); }
        if (a2) { const u32* pl = lds + (2 + sl2) * PS2; w_um2 = ld2u(pl + off_up); w_dn2 = ld2u(pl + off_dn); }
        if (a3) { const u32* pl = lds + (4 + sl3) * PS2; w_um3 = ld2u(pl + off_up); w_dn3 = ld2u(pl + off_dn); }

        f4 nv1 = s1l0, nv2 = s2l0, nv3 = s3l0, nv4 = s4l0;

        // ---- stage 1: input regs + ring0 -> ring1 ----
        if (a1) {
            const int p = t - 1;
            f4 c  = l0;
            f4 zm = (!ST && p == 0)      ? c : l1;
            f4 zp = (!ST && p == D1 - 1) ? c : nxt;
            const float czf = (!ST && (p == 0 || p == D1 - 1)) ? COEFF : CHALF;
            nv1 = sten<FIX2>(c, zm, zp, upk4(w_um1), upk4(w_dn1), csr, cx, czf, xlo, xhi);
            stb(lds + (2 + sl1) * PS2 + off_c, nv1);
        }

        // ---- issue reads for stage 4, then stage 2 compute ----
        uint2 w_um4 = {0, 0}, w_dn4 = {0, 0};
        if (a4) { const u32* pl = lds + (6 + sl4) * PS2; w_um4 = ld2u(pl + off_up); w_dn4 = ld2u(pl + off_dn); }
        if (a2) {
            const int p = t - 2;
            f4 c  = s1l0;
            f4 zm = (!ST && p == 0)      ? c : s1l1;
            f4 zp = (!ST && p == D1 - 1) ? c : nv1;
            const float czf = (!ST && (p == 0 || p == D1 - 1)) ? COEFF : CHALF;
            nv2 = sten<FIX2>(c, zm, zp, upk4(w_um2), upk4(w_dn2), csr, cx, czf, xlo, xhi);
            stb(lds + (4 + sl2) * PS2 + off_c, nv2);
        }

        // ---- issue reads for stage 5, then stage 3 compute ----
        uint2 w_um5 = {0, 0}, w_dn5 = {0, 0};
        if (a5) { const u32* pl = lds + (8 + sl5) * PS2; w_um5 = ld2u(pl + off_up); w_dn5 = ld2u(pl + off_dn); }
        if (a3) {
            const int p = t - 3;
            f4 c  = s2l0;
            f4 zm = (!ST && p == 0)      ? c : s2l1;
            f4 zp = (!ST && p == D1 - 1) ? c : nv2;
            const float czf = (!ST && (p == 0 || p == D1 - 1)) ? COEFF : CHALF;
            nv3 = sten<FIX2>(c, zm, zp, upk4(w_um3), upk4(w_dn3), csr, cx, czf, xlo, xhi);
            stb(lds + (6 + sl3) * PS2 + off_c, nv3);
        }

        // ---- stage 4 ----
        if (a4) {
            const int p = t - 4;
            f4 c  = s3l0;
            f4 zm = (!ST && p == 0)      ? c : s3l1;
            f4 zp = (!ST && p == D1 - 1) ? c : nv3;
            const float czf = (!ST && (p == 0 || p == D1 - 1)) ? COEFF : CHALF;
            nv4 = sten<FIX2>(c, zm, zp, upk4(w_um4), upk4(w_dn4), csr, cx, czf, xlo, xhi);
            stb(lds + (8 + sl4) * PS2 + off_c, nv4);
        }

        // ---- stage 5 -> global ----
        if (a5) {
            const int p = t - 5;
            f4 c  = s4l0;
            f4 zm = (!ST && p == 0)      ? c : s4l1;
            f4 zp = (!ST && p == D1 - 1) ? c : nv4;
            const float czf = (!ST && (p == 0 || p == D1 - 1)) ? COEFF : CHALF;
            f4 o = sten<FIX2>(c, zm, zp, upk4(w_um5), upk4(w_dn5), csr, cx, czf, xlo, xhi);
            if (PASS == 0) {
                u16* dp = dbh + (size_t)p * D2;
                if (c4 + 0 >= 5 && c4 + 0 <= 58) dp[c4 + 0] = f2bf(o.x);
                if (c4 + 1 >= 5 && c4 + 1 <= 58) dp[c4 + 1] = f2bf(o.y);
                if (c4 + 2 >= 5 && c4 + 2 <= 58) dp[c4 + 2] = f2bf(o.z);
                if (c4 + 3 >= 5 && c4 + 3 <= 58) dp[c4 + 3] = f2bf(o.w);
            } else {
                float* dp = dbf + (size_t)p * D2;
                if (c4 >= 8 && c4 <= 52) {                  // fully-valid runs
                    st4(dp + c4, o);
                } else if (c4 == 4) {                       // cols 5,6,7
                    dp[5] = o.y; *(float2*)(dp + 6) = make_float2(o.z, o.w);
                } else if (c4 == 56) {                      // cols 56,57,58
                    *(float2*)(dp + 56) = make_float2(o.x, o.y); dp[58] = o.z;
                }                                           // c4==0,60: all halo
            }
        }

        // ---- commit input plane t ----
        if (ST || t < hiIn) stb(lds + (ST ? PAR : (t & 1)) * PS2 + off_c, nxt);

        // ---- roll lags ----
        l1 = l0; l0 = nxt; nxt = nx2; nx2 = tmp;
        s1l1 = s1l0; s1l0 = nv1;
        s2l1 = s2l0; s2l0 = nv2;
        s3l1 = s3l0; s3l0 = nv3;
        s4l1 = s4l0; s4l0 = nv4;
        __syncthreads();
    };

    int tSlo = t0 + 11; tSlo += (tSlo & 1);
    const int tEnd = bE + 4;
    const int tShi = min(bE + 4, D1 - 1);
    int t = t0;
    const int tP = min(tSlo, tEnd + 1);
#pragma unroll 1
    for (; t < tP; ++t) body(t, PG{});
#pragma unroll 1
    for (; t + 1 <= tShi; t += 2) { body(t, P0{}); body(t + 1, P1{}); }
#pragma unroll 1
    for (; t <= tEnd; ++t) body(t, PG{});
}

// Max-only launch bound: allocator picks natural 64 VGPR, zero scratch (R15-
// R18 verified). Forced min-waves caps collapse to 32-40 VGPR + spill; for
// 1024-thread blocks the allocator pins 64 VGPR regardless (R19/R20), which
// this 5-stage body fits exactly.
template<int PASS>
__global__ __launch_bounds__(1024) void diffusion_fused(const void* __restrict__ src,
                                                        void* __restrict__ dst) {
    __shared__ __align__(16) u32 lds[10 * PS2];   // 81920 B

    const int b = swz(blockIdx.x);
    const int seg = b / NSTRIP;
    const int strip = b - seg * NSTRIP;
    const int o2 = min(strip * TT, D2 - TT);
    const int h2 = o2 - KST;
    const int a  = seg * SEGLEN;
    const int bE = min(a + SEGLEN, D1);

    const int r  = threadIdx.x >> 4;          // 0..63 over d0 (no halo)
    const int c4 = (threadIdx.x & 15) << 2;   // 0..60 over d2 strip

    if (o2 == 0 || o2 == D2 - TT) run<PASS, true >(src, dst, &lds[0], r, c4, h2, a, bE);
    else                          run<PASS, false>(src, dst, &lds[0], r, c4, h2, a, bE);
}

extern "C" void kernel_launch(void* const* d_in, const int* in_sizes, int n_in,
                              void* d_out, int out_size, void* d_ws, size_t ws_size,
                              hipStream_t stream) {
    const void* x  = d_in[0];
    void* out = d_out;
    void* ws  = d_ws;

    const dim3 grid(NWG);
    const dim3 block(1024);

    diffusion_fused<0><<<grid, block, 0, stream>>>(x, ws);    // f32 -> bf16 ws
    diffusion_fused<1><<<grid, block, 0, stream>>>(ws, out);  // bf16 ws -> f32
}